// Round 3
// baseline (578.702 us; speedup 1.0000x reference)
//
#include <hip/hip_runtime.h>
#include <math.h>

#define DH 512
#define CC 64
#define NB 2048
#define SCALE 0.044194173824159216f   // 1/sqrt(512)

// ---------------- wave helpers ----------------
__device__ __forceinline__ float wsum(float v) {
#pragma unroll
  for (int off = 32; off; off >>= 1) v += __shfl_xor(v, off, 64);
  return v;
}

// ============================================================================
// pre_kernel: blocks 0..255 compute wsA = W_q^T @ W_k (rows 0..1535) and
// wsM = W_v^T @ W_k (rows 1536..2047) with 64x64 tiles; block 256 does the
// bool-layout detection for `double` -> need[b] in {1,2}.
// ============================================================================
__global__ __launch_bounds__(128) void pre_kernel(const float* __restrict__ Wq,
                                                  const float* __restrict__ Wv,
                                                  const float* __restrict__ Wk,
                                                  float* __restrict__ Aout,
                                                  float* __restrict__ Mout,
                                                  const unsigned char* __restrict__ dbl,
                                                  int* __restrict__ need) {
  const int bx = blockIdx.x;
  const int t = threadIdx.x;
  if (bx == 256) {
    __shared__ int flagNZ, flagFP;
    if (t == 0) { flagNZ = 0; flagFP = 0; }
    __syncthreads();
    int nz = 0, fp = 0;
    for (int i = t; i < NB; i += 128) {
      if (i & 3) {
        unsigned char v = dbl[i];
        nz |= (v != 0);
        fp |= (v == 0x3f) | (v == 0x80);
      }
    }
    if (nz) atomicOr(&flagNZ, 1);
    if (fp) atomicOr(&flagFP, 1);
    __syncthreads();
    const int isFP = flagFP, isByte = flagNZ && !flagFP;
    for (int i = t; i < NB; i += 128) {
      int v;
      if (isFP)        v = (((const float*)dbl)[i] != 0.0f);
      else if (isByte) v = (dbl[i] != 0);
      else             v = (((const int*)dbl)[i] != 0);
      need[i] = v ? 2 : 1;
    }
    return;
  }
  __shared__ float As[16][64];
  __shared__ float Bs[16][64];
  const int mt = bx >> 3, nt = bx & 7;
  const int m0 = mt * 64, n0 = nt * 64;
  const bool isQ = (m0 < 1536);
  const float* Acol = isQ ? (Wq + m0) : (Wv + (m0 - 1536));
  const int lda = isQ ? 1536 : 512;
  float* Cout = isQ ? (Aout + (size_t)m0 * 512) : (Mout + (size_t)(m0 - 1536) * 512);
  const int lr = t >> 3;
  const int lc = (t & 7) << 3;
  const int tx = t & 15, ty = t >> 4;

  float4 ra0, ra1, rb0, rb1;
  ra0 = *(const float4*)&Acol[(size_t)lr * lda + lc];
  ra1 = *(const float4*)&Acol[(size_t)lr * lda + lc + 4];
  rb0 = *(const float4*)&Wk[(size_t)lr * 512 + n0 + lc];
  rb1 = *(const float4*)&Wk[(size_t)lr * 512 + n0 + lc + 4];
  float acc[8][4] = {};
  for (int k0 = 0; k0 < 512; k0 += 16) {
    __syncthreads();
    *(float4*)&As[lr][lc] = ra0;
    *(float4*)&As[lr][lc + 4] = ra1;
    *(float4*)&Bs[lr][lc] = rb0;
    *(float4*)&Bs[lr][lc + 4] = rb1;
    __syncthreads();
    if (k0 + 16 < 512) {
      const int kn = k0 + 16 + lr;
      ra0 = *(const float4*)&Acol[(size_t)kn * lda + lc];
      ra1 = *(const float4*)&Acol[(size_t)kn * lda + lc + 4];
      rb0 = *(const float4*)&Wk[(size_t)kn * 512 + n0 + lc];
      rb1 = *(const float4*)&Wk[(size_t)kn * 512 + n0 + lc + 4];
    }
#pragma unroll
    for (int k = 0; k < 16; ++k) {
      float4 a0 = *(float4*)&As[k][ty << 3];
      float4 a1 = *(float4*)&As[k][(ty << 3) + 4];
      float4 b  = *(float4*)&Bs[k][tx << 2];
      float av[8] = {a0.x, a0.y, a0.z, a0.w, a1.x, a1.y, a1.z, a1.w};
      float bv[4] = {b.x, b.y, b.z, b.w};
#pragma unroll
      for (int i = 0; i < 8; ++i)
#pragma unroll
        for (int j = 0; j < 4; ++j) acc[i][j] = fmaf(av[i], bv[j], acc[i][j]);
    }
  }
#pragma unroll
  for (int i = 0; i < 8; ++i) {
    float4 o = {acc[i][0], acc[i][1], acc[i][2], acc[i][3]};
    *(float4*)&Cout[(size_t)((ty << 3) + i) * 512 + n0 + (tx << 2)] = o;
  }
}

// ============================================================================
// gemm_nn2p: 128x64 tile, 8x4 micro, reg-prefetch, split-K to PARTIAL buffers
// (only used for qk = context @ A now)
// ============================================================================
#define AS_STR 132

__global__ __launch_bounds__(256) void gemm_nn2p(const float* __restrict__ A0,
                                                 const float* __restrict__ A1,
                                                 const float* __restrict__ A2,
                                                 const float* __restrict__ B,
                                                 float* __restrict__ Cp,
                                                 int kchunk) {
  __shared__ float As[16 * AS_STR];
  __shared__ float Bs[16 * 64];
  const int t = threadIdx.x;
  const int m0 = blockIdx.x * 128, n0 = blockIdx.y * 64;
  const int kbeg = blockIdx.z * kchunk, kend = kbeg + kchunk;
  float* C = Cp + (size_t)blockIdx.z * (NB * DH);
  const int tx = t & 15, ty = t >> 4;
  const int ar0 = t >> 2;
  const int ak4 = (t & 3) << 2;
  const int bk = t >> 4, bn4 = (t & 15) << 2;

  float4 ra0, ra1, rb;
  {
    const float* base = (kbeg < 512) ? A0 : ((kbeg < 1024) ? A1 : A2);
    const int kk = kbeg & 511;
    ra0 = *(const float4*)&base[(size_t)(m0 + ar0) * 512 + kk + ak4];
    ra1 = *(const float4*)&base[(size_t)(m0 + ar0 + 64) * 512 + kk + ak4];
    rb  = *(const float4*)&B[(size_t)(kbeg + bk) * 512 + n0 + bn4];
  }
  float acc[8][4] = {};
  for (int k0 = kbeg; k0 < kend; k0 += 16) {
    __syncthreads();
    As[(ak4 + 0) * AS_STR + ar0] = ra0.x;
    As[(ak4 + 1) * AS_STR + ar0] = ra0.y;
    As[(ak4 + 2) * AS_STR + ar0] = ra0.z;
    As[(ak4 + 3) * AS_STR + ar0] = ra0.w;
    As[(ak4 + 0) * AS_STR + ar0 + 64] = ra1.x;
    As[(ak4 + 1) * AS_STR + ar0 + 64] = ra1.y;
    As[(ak4 + 2) * AS_STR + ar0 + 64] = ra1.z;
    As[(ak4 + 3) * AS_STR + ar0 + 64] = ra1.w;
    *(float4*)&Bs[bk * 64 + bn4] = rb;
    __syncthreads();
    if (k0 + 16 < kend) {
      const int kn = k0 + 16;
      const float* base = (kn < 512) ? A0 : ((kn < 1024) ? A1 : A2);
      const int kk = kn & 511;
      ra0 = *(const float4*)&base[(size_t)(m0 + ar0) * 512 + kk + ak4];
      ra1 = *(const float4*)&base[(size_t)(m0 + ar0 + 64) * 512 + kk + ak4];
      rb  = *(const float4*)&B[(size_t)(kn + bk) * 512 + n0 + bn4];
    }
#pragma unroll
    for (int k = 0; k < 16; ++k) {
      float4 a0 = *(float4*)&As[k * AS_STR + (ty << 3)];
      float4 a1 = *(float4*)&As[k * AS_STR + (ty << 3) + 4];
      float4 b  = *(float4*)&Bs[k * 64 + (tx << 2)];
      float av[8] = {a0.x, a0.y, a0.z, a0.w, a1.x, a1.y, a1.z, a1.w};
      float bv[4] = {b.x, b.y, b.z, b.w};
#pragma unroll
      for (int i = 0; i < 8; ++i)
#pragma unroll
        for (int j = 0; j < 4; ++j) acc[i][j] = fmaf(av[i], bv[j], acc[i][j]);
    }
  }
#pragma unroll
  for (int i = 0; i < 8; ++i) {
    float4 o = {acc[i][0], acc[i][1], acc[i][2], acc[i][3]};
    *(float4*)&C[(size_t)(m0 + (ty << 3) + i) * 512 + n0 + (tx << 2)] = o;
  }
}

// ============================================================================
// fused_kernel: pass1 + gemm2 + pass2, two batch-rows per block.
// Streaming phases (A1, C) issue pure load+fma into independent per-lane
// partials in GROUPS OF 8 cores (16 float4 loads in flight ≈ 64 VGPRs of
// payload — fits the 128-VGPR cap at 4 blocks/CU without spilling), then do
// all 16 wave-reductions as an ILP block. A2 re-reads the just-fetched
// 32 KB/wave from L1/L2 for the V-weighted accumulate.
// ============================================================================
__global__ __launch_bounds__(256, 4) void fused_kernel(const float* __restrict__ HtC,
                                                       const int* __restrict__ caps,
                                                       const int* __restrict__ dists,
                                                       const float* __restrict__ Qkp,
                                                       const float* __restrict__ Mm,
                                                       const float* __restrict__ cap_emb,
                                                       const float* __restrict__ dist_emb,
                                                       const int* __restrict__ need,
                                                       float* __restrict__ out) {
  const int t = threadIdx.x;
  const int wv = t >> 6, ln = t & 63;
  const int b0 = blockIdx.x << 1;

  __shared__ float qk[2][DH];
  __shared__ float Gws[2][DH];
  __shared__ float gks[2][DH];
  __shared__ float gkp[2][2][DH];
  __shared__ float accs[4][DH];
  __shared__ float ec[CC];          // reused as ulog in phase C
  __shared__ float capQ[2][11], distQ[2][3];
  __shared__ float capE[11], distE[3];
  __shared__ float capG[2][11], distG[2][3];
  __shared__ float lsum_s;
  __shared__ int capsS[2][CC], distsS[2][CC];

  // ---- preload caps/dists for both rows ----
  if (t < 128) {
    int hh = t >> 6, c = t & 63;
    capsS[hh][c] = caps[(size_t)(b0 + hh) * CC + c];
    distsS[hh][c] = dists[(size_t)(b0 + hh) * CC + c];
  }

  // ---- qk for both rows: sum of 4 split-K partials ----
#pragma unroll
  for (int h = 0; h < 2; ++h) {
    const size_t bo = (size_t)(b0 + h) * DH;
    float q0 = 0.f, q1 = 0.f;
#pragma unroll
    for (int z = 0; z < 4; ++z) {
      q0 += Qkp[(size_t)z * NB * DH + bo + t];
      q1 += Qkp[(size_t)z * NB * DH + bo + 256 + t];
    }
    qk[h][t] = q0;
    qk[h][t + 256] = q1;
  }
  __syncthreads();

  // ---- capQ/distQ (embedding . qk) for both rows ----
#pragma unroll
  for (int h = 0; h < 2; ++h) {
#pragma unroll
    for (int r = 0; r < 3; ++r) {
      int v = wv + (r << 2);
      if (v < 11) {
        float s = 0.f;
#pragma unroll
        for (int j = 0; j < 8; ++j) s = fmaf(cap_emb[v * DH + ln + (j << 6)], qk[h][ln + (j << 6)], s);
        s = wsum(s);
        if (ln == 0) capQ[h][v] = s;
      }
    }
    if (wv < 3) {
      float s = 0.f;
#pragma unroll
      for (int j = 0; j < 8; ++j) s = fmaf(dist_emb[wv * DH + ln + (j << 6)], qk[h][ln + (j << 6)], s);
      s = wsum(s);
      if (ln == 0) distQ[h][wv] = s;
    }
  }

  // ---- phase A: glimpse attention over each row ----
  for (int h = 0; h < 2; ++h) {
    const int b = b0 + h;
    if (t < 11) capE[t] = 0.f;
    if (t < 3) distE[t] = 0.f;
    __syncthreads();   // also covers capQ/distQ + capsS writes on h==0
    const float4* qk4 = (const float4*)qk[h];
    float4 q1 = qk4[ln];
    float4 q2 = qk4[64 + ln];
    const float* hb = HtC + (size_t)b * CC * DH;

    // A1: pure stream in two groups of 8 (bounds in-flight loads ~16 float4)
    float sp[16];
#pragma unroll
    for (int g = 0; g < 2; ++g) {
#pragma unroll
      for (int i = 0; i < 8; ++i) {
        const int c = (wv << 4) + (g << 3) + i;
        const float4* h4 = (const float4*)(hb + (size_t)c * DH);
        float4 h1 = h4[ln];
        float4 h2 = h4[64 + ln];
        sp[(g << 3) + i] = h1.x * q1.x + h1.y * q1.y + h1.z * q1.z + h1.w * q1.w +
                           h2.x * q2.x + h2.y * q2.y + h2.z * q2.z + h2.w * q2.w;
      }
    }
    // 16 ILP-overlapped wave reductions
#pragma unroll
    for (int i = 0; i < 16; ++i) sp[i] = wsum(sp[i]);
    float ei[16];
#pragma unroll
    for (int i = 0; i < 16; ++i) {
      int c = (wv << 4) + i;
      float logit = SCALE * (sp[i] + capQ[h][capsS[h][c]] + distQ[h][distsS[h][c]]);
      ei[i] = __expf(logit);
    }
    if (ln == 0) {
#pragma unroll
      for (int i = 0; i < 16; ++i) ec[(wv << 4) + i] = ei[i];
    }
    // A2: re-read (L1/L2-hot) and accumulate e * h
    float a0 = 0.f, a1 = 0.f, a2 = 0.f, a3 = 0.f, a4 = 0.f, a5 = 0.f, a6 = 0.f, a7 = 0.f;
#pragma unroll
    for (int i = 0; i < 16; ++i) {
      const float4* h4 = (const float4*)(hb + (size_t)((wv << 4) + i) * DH);
      float4 h1 = h4[ln];
      float4 h2 = h4[64 + ln];
      a0 = fmaf(ei[i], h1.x, a0); a1 = fmaf(ei[i], h1.y, a1);
      a2 = fmaf(ei[i], h1.z, a2); a3 = fmaf(ei[i], h1.w, a3);
      a4 = fmaf(ei[i], h2.x, a4); a5 = fmaf(ei[i], h2.y, a5);
      a6 = fmaf(ei[i], h2.z, a6); a7 = fmaf(ei[i], h2.w, a7);
    }
    {
      int d0 = ln << 2;
      accs[wv][d0 + 0] = a0; accs[wv][d0 + 1] = a1;
      accs[wv][d0 + 2] = a2; accs[wv][d0 + 3] = a3;
      accs[wv][256 + d0 + 0] = a4; accs[wv][256 + d0 + 1] = a5;
      accs[wv][256 + d0 + 2] = a6; accs[wv][256 + d0 + 3] = a7;
    }
    __syncthreads();
    if (t < CC) {
      float e = ec[t];
      float l = wsum(e);
      if (t == 0) lsum_s = l;
      atomicAdd(&capE[capsS[h][t]], e);
      atomicAdd(&distE[distsS[h][t]], e);
    }
    __syncthreads();
    const float rinv = 1.0f / lsum_s;
#pragma unroll
    for (int dd = 0; dd < 2; ++dd) {
      int d = t + (dd << 8);
      float g = accs[0][d] + accs[1][d] + accs[2][d] + accs[3][d];
#pragma unroll
      for (int v = 0; v < 11; ++v) g = fmaf(capE[v], cap_emb[v * DH + d], g);
#pragma unroll
      for (int v = 0; v < 3; ++v) g = fmaf(distE[v], dist_emb[v * DH + d], g);
      Gws[h][d] = g * rinv;
    }
    __syncthreads();
  }

  // ---- phase B: gk[h] = Gw[h] @ M, M streamed once (coalesced float4) ----
  {
    const int e4 = (t & 127) << 2;   // 128 threads cover e in [0,512) as float4
    const int half = t >> 7;         // d-range split: [0,256) / [256,512)
    const float* Mp = Mm + (size_t)(half << 8) * DH + e4;
    const float* g0p = &Gws[0][half << 8];
    const float* g1p = &Gws[1][half << 8];
    float s00 = 0.f, s01 = 0.f, s02 = 0.f, s03 = 0.f;
    float s10 = 0.f, s11 = 0.f, s12 = 0.f, s13 = 0.f;
#pragma unroll 8
    for (int d = 0; d < 256; ++d) {
      float4 m4 = *(const float4*)&Mp[(size_t)d * DH];
      float g0 = g0p[d];
      float g1 = g1p[d];
      s00 = fmaf(g0, m4.x, s00); s01 = fmaf(g0, m4.y, s01);
      s02 = fmaf(g0, m4.z, s02); s03 = fmaf(g0, m4.w, s03);
      s10 = fmaf(g1, m4.x, s10); s11 = fmaf(g1, m4.y, s11);
      s12 = fmaf(g1, m4.z, s12); s13 = fmaf(g1, m4.w, s13);
    }
    gkp[half][0][e4 + 0] = s00; gkp[half][0][e4 + 1] = s01;
    gkp[half][0][e4 + 2] = s02; gkp[half][0][e4 + 3] = s03;
    gkp[half][1][e4 + 0] = s10; gkp[half][1][e4 + 1] = s11;
    gkp[half][1][e4 + 2] = s12; gkp[half][1][e4 + 3] = s13;
  }
  __syncthreads();
#pragma unroll
  for (int h = 0; h < 2; ++h) {
    gks[h][t] = gkp[0][h][t] + gkp[1][h][t];
    gks[h][t + 256] = gkp[0][h][t + 256] + gkp[1][h][t + 256];
  }
  __syncthreads();

  // ---- capG/distG (embedding . gk) for both rows ----
#pragma unroll
  for (int h = 0; h < 2; ++h) {
#pragma unroll
    for (int r = 0; r < 3; ++r) {
      int v = wv + (r << 2);
      if (v < 11) {
        float s = 0.f;
#pragma unroll
        for (int j = 0; j < 8; ++j) s = fmaf(cap_emb[v * DH + ln + (j << 6)], gks[h][ln + (j << 6)], s);
        s = wsum(s);
        if (ln == 0) capG[h][v] = s;
      }
    }
    if (wv < 3) {
      float s = 0.f;
#pragma unroll
      for (int j = 0; j < 8; ++j) s = fmaf(dist_emb[wv * DH + ln + (j << 6)], gks[h][ln + (j << 6)], s);
      s = wsum(s);
      if (ln == 0) distG[h][wv] = s;
    }
  }
  __syncthreads();

  // ---- phase C: pointer logits + capacity-masked softmax (b1 first) ----
  for (int h = 1; h >= 0; --h) {
    const int b = b0 + h;
    const float4* gk4 = (const float4*)gks[h];
    float4 q1 = gk4[ln];
    float4 q2 = gk4[64 + ln];
    const float* hb = HtC + (size_t)b * CC * DH;
    float sp[16];
#pragma unroll
    for (int g = 0; g < 2; ++g) {
#pragma unroll
      for (int i = 0; i < 8; ++i) {
        const int c = (wv << 4) + (g << 3) + i;
        const float4* h4 = (const float4*)(hb + (size_t)c * DH);
        float4 h1 = h4[ln];
        float4 h2 = h4[64 + ln];
        sp[(g << 3) + i] = h1.x * q1.x + h1.y * q1.y + h1.z * q1.z + h1.w * q1.w +
                           h2.x * q2.x + h2.y * q2.y + h2.z * q2.z + h2.w * q2.w;
      }
    }
#pragma unroll
    for (int i = 0; i < 16; ++i) sp[i] = wsum(sp[i]);
    if (ln == 0) {
#pragma unroll
      for (int i = 0; i < 16; ++i) {
        int c = (wv << 4) + i;
        ec[c] = SCALE * (sp[i] + capG[h][capsS[h][c]] + distG[h][distsS[h][c]]);
      }
    }
    __syncthreads();
    if (t < CC) {
      int nb = need[b];
      float x = ec[t];
      if (capsS[h][t] < nb) x = -INFINITY;
      float m = x;
#pragma unroll
      for (int off = 32; off; off >>= 1) m = fmaxf(m, __shfl_xor(m, off, 64));
      float e = __expf(x - m);
      float ssum = wsum(e);
      out[(size_t)b * CC + t] = e / ssum;
    }
    __syncthreads();
  }
}

// ---------------- launch ----------------
extern "C" void kernel_launch(void* const* d_in, const int* in_sizes, int n_in,
                              void* d_out, int out_size, void* d_ws, size_t ws_size,
                              hipStream_t stream) {
  const float* HtC      = (const float*)d_in[0];
  const int* caps       = (const int*)d_in[1];
  const int* dists      = (const int*)d_in[2];
  const float* H_X      = (const float*)d_in[3];
  const float* Ht_S     = (const float*)d_in[4];
  const float* Eq_Q     = (const float*)d_in[5];
  const unsigned char* dbl = (const unsigned char*)d_in[6];
  const float* cap_emb  = (const float*)d_in[7];
  const float* dist_emb = (const float*)d_in[8];
  const float* W_q      = (const float*)d_in[9];
  const float* W_k      = (const float*)d_in[10];
  const float* W_v      = (const float*)d_in[11];
  float* out = (float*)d_out;

  float* ws     = (float*)d_ws;
  float* wsA    = ws;                        // [1536,512]     A = W_q^T @ W_k
  float* wsM    = wsA + 1536 * 512;          // [512,512]      M = W_v^T @ W_k
  float* wsQkp  = wsM + 512 * 512;           // [4][2048,512]  Qk split-K partials
  int* wsNeed   = (int*)(wsQkp + 4 * 2048 * 512);

  pre_kernel<<<257, 128, 0, stream>>>(W_q, W_v, W_k, wsA, wsM, dbl, wsNeed);
  gemm_nn2p<<<dim3(16, 8, 4), 256, 0, stream>>>(H_X, Ht_S, Eq_Q, wsA, wsQkp, 384);
  fused_kernel<<<NB / 2, 256, 0, stream>>>(HtC, caps, dists, wsQkp, wsM,
                                           cap_emb, dist_emb, wsNeed, out);
}

// Round 4
// 553.870 us; speedup vs baseline: 1.0448x; 1.0448x over previous
//
#include <hip/hip_runtime.h>
#include <math.h>

#define DH 512
#define CC 64
#define NB 2048
#define SCALE 0.044194173824159216f   // 1/sqrt(512)

// padded index for column-sliced LDS arrays: stride 36 floats per 32-elem row
// (144 B: 16B-aligned for b128, and (36l+4j)%32 spreads banks ≤2-way = free)
#define PD(d) ((((d) >> 5) * 36) + ((d) & 31))

// ---------------- wave helpers ----------------
__device__ __forceinline__ float wsum(float v) {
#pragma unroll
  for (int off = 32; off; off >>= 1) v += __shfl_xor(v, off, 64);
  return v;
}

// ============================================================================
// pre_kernel: blocks 0..255 compute wsA = W_q^T @ W_k (rows 0..1535) and
// wsM = W_v^T @ W_k (rows 1536..2047) with 64x64 tiles; block 256 does the
// bool-layout detection for `double` -> need[b] in {1,2}.
// ============================================================================
__global__ __launch_bounds__(128) void pre_kernel(const float* __restrict__ Wq,
                                                  const float* __restrict__ Wv,
                                                  const float* __restrict__ Wk,
                                                  float* __restrict__ Aout,
                                                  float* __restrict__ Mout,
                                                  const unsigned char* __restrict__ dbl,
                                                  int* __restrict__ need) {
  const int bx = blockIdx.x;
  const int t = threadIdx.x;
  if (bx == 256) {
    __shared__ int flagNZ, flagFP;
    if (t == 0) { flagNZ = 0; flagFP = 0; }
    __syncthreads();
    int nz = 0, fp = 0;
    for (int i = t; i < NB; i += 128) {
      if (i & 3) {
        unsigned char v = dbl[i];
        nz |= (v != 0);
        fp |= (v == 0x3f) | (v == 0x80);
      }
    }
    if (nz) atomicOr(&flagNZ, 1);
    if (fp) atomicOr(&flagFP, 1);
    __syncthreads();
    const int isFP = flagFP, isByte = flagNZ && !flagFP;
    for (int i = t; i < NB; i += 128) {
      int v;
      if (isFP)        v = (((const float*)dbl)[i] != 0.0f);
      else if (isByte) v = (dbl[i] != 0);
      else             v = (((const int*)dbl)[i] != 0);
      need[i] = v ? 2 : 1;
    }
    return;
  }
  __shared__ float As[16][64];
  __shared__ float Bs[16][64];
  const int mt = bx >> 3, nt = bx & 7;
  const int m0 = mt * 64, n0 = nt * 64;
  const bool isQ = (m0 < 1536);
  const float* Acol = isQ ? (Wq + m0) : (Wv + (m0 - 1536));
  const int lda = isQ ? 1536 : 512;
  float* Cout = isQ ? (Aout + (size_t)m0 * 512) : (Mout + (size_t)(m0 - 1536) * 512);
  const int lr = t >> 3;
  const int lc = (t & 7) << 3;
  const int tx = t & 15, ty = t >> 4;

  float4 ra0, ra1, rb0, rb1;
  ra0 = *(const float4*)&Acol[(size_t)lr * lda + lc];
  ra1 = *(const float4*)&Acol[(size_t)lr * lda + lc + 4];
  rb0 = *(const float4*)&Wk[(size_t)lr * 512 + n0 + lc];
  rb1 = *(const float4*)&Wk[(size_t)lr * 512 + n0 + lc + 4];
  float acc[8][4] = {};
  for (int k0 = 0; k0 < 512; k0 += 16) {
    __syncthreads();
    *(float4*)&As[lr][lc] = ra0;
    *(float4*)&As[lr][lc + 4] = ra1;
    *(float4*)&Bs[lr][lc] = rb0;
    *(float4*)&Bs[lr][lc + 4] = rb1;
    __syncthreads();
    if (k0 + 16 < 512) {
      const int kn = k0 + 16 + lr;
      ra0 = *(const float4*)&Acol[(size_t)kn * lda + lc];
      ra1 = *(const float4*)&Acol[(size_t)kn * lda + lc + 4];
      rb0 = *(const float4*)&Wk[(size_t)kn * 512 + n0 + lc];
      rb1 = *(const float4*)&Wk[(size_t)kn * 512 + n0 + lc + 4];
    }
#pragma unroll
    for (int k = 0; k < 16; ++k) {
      float4 a0 = *(float4*)&As[k][ty << 3];
      float4 a1 = *(float4*)&As[k][(ty << 3) + 4];
      float4 b  = *(float4*)&Bs[k][tx << 2];
      float av[8] = {a0.x, a0.y, a0.z, a0.w, a1.x, a1.y, a1.z, a1.w};
      float bv[4] = {b.x, b.y, b.z, b.w};
#pragma unroll
      for (int i = 0; i < 8; ++i)
#pragma unroll
        for (int j = 0; j < 4; ++j) acc[i][j] = fmaf(av[i], bv[j], acc[i][j]);
    }
  }
#pragma unroll
  for (int i = 0; i < 8; ++i) {
    float4 o = {acc[i][0], acc[i][1], acc[i][2], acc[i][3]};
    *(float4*)&Cout[(size_t)((ty << 3) + i) * 512 + n0 + (tx << 2)] = o;
  }
}

// ============================================================================
// gemm_nn2p: 128x64 tile, 8x4 micro, reg-prefetch, split-K to PARTIAL buffers
// (only used for qk = context @ A now)
// ============================================================================
#define AS_STR 132

__global__ __launch_bounds__(256) void gemm_nn2p(const float* __restrict__ A0,
                                                 const float* __restrict__ A1,
                                                 const float* __restrict__ A2,
                                                 const float* __restrict__ B,
                                                 float* __restrict__ Cp,
                                                 int kchunk) {
  __shared__ float As[16 * AS_STR];
  __shared__ float Bs[16 * 64];
  const int t = threadIdx.x;
  const int m0 = blockIdx.x * 128, n0 = blockIdx.y * 64;
  const int kbeg = blockIdx.z * kchunk, kend = kbeg + kchunk;
  float* C = Cp + (size_t)blockIdx.z * (NB * DH);
  const int tx = t & 15, ty = t >> 4;
  const int ar0 = t >> 2;
  const int ak4 = (t & 3) << 2;
  const int bk = t >> 4, bn4 = (t & 15) << 2;

  float4 ra0, ra1, rb;
  {
    const float* base = (kbeg < 512) ? A0 : ((kbeg < 1024) ? A1 : A2);
    const int kk = kbeg & 511;
    ra0 = *(const float4*)&base[(size_t)(m0 + ar0) * 512 + kk + ak4];
    ra1 = *(const float4*)&base[(size_t)(m0 + ar0 + 64) * 512 + kk + ak4];
    rb  = *(const float4*)&B[(size_t)(kbeg + bk) * 512 + n0 + bn4];
  }
  float acc[8][4] = {};
  for (int k0 = kbeg; k0 < kend; k0 += 16) {
    __syncthreads();
    As[(ak4 + 0) * AS_STR + ar0] = ra0.x;
    As[(ak4 + 1) * AS_STR + ar0] = ra0.y;
    As[(ak4 + 2) * AS_STR + ar0] = ra0.z;
    As[(ak4 + 3) * AS_STR + ar0] = ra0.w;
    As[(ak4 + 0) * AS_STR + ar0 + 64] = ra1.x;
    As[(ak4 + 1) * AS_STR + ar0 + 64] = ra1.y;
    As[(ak4 + 2) * AS_STR + ar0 + 64] = ra1.z;
    As[(ak4 + 3) * AS_STR + ar0 + 64] = ra1.w;
    *(float4*)&Bs[bk * 64 + bn4] = rb;
    __syncthreads();
    if (k0 + 16 < kend) {
      const int kn = k0 + 16;
      const float* base = (kn < 512) ? A0 : ((kn < 1024) ? A1 : A2);
      const int kk = kn & 511;
      ra0 = *(const float4*)&base[(size_t)(m0 + ar0) * 512 + kk + ak4];
      ra1 = *(const float4*)&base[(size_t)(m0 + ar0 + 64) * 512 + kk + ak4];
      rb  = *(const float4*)&B[(size_t)(kn + bk) * 512 + n0 + bn4];
    }
#pragma unroll
    for (int k = 0; k < 16; ++k) {
      float4 a0 = *(float4*)&As[k * AS_STR + (ty << 3)];
      float4 a1 = *(float4*)&As[k * AS_STR + (ty << 3) + 4];
      float4 b  = *(float4*)&Bs[k * 64 + (tx << 2)];
      float av[8] = {a0.x, a0.y, a0.z, a0.w, a1.x, a1.y, a1.z, a1.w};
      float bv[4] = {b.x, b.y, b.z, b.w};
#pragma unroll
      for (int i = 0; i < 8; ++i)
#pragma unroll
        for (int j = 0; j < 4; ++j) acc[i][j] = fmaf(av[i], bv[j], acc[i][j]);
    }
  }
#pragma unroll
  for (int i = 0; i < 8; ++i) {
    float4 o = {acc[i][0], acc[i][1], acc[i][2], acc[i][3]};
    *(float4*)&C[(size_t)(m0 + (ty << 3) + i) * 512 + n0 + (tx << 2)] = o;
  }
}

// ============================================================================
// fused_kernel: pass1 + gemm2 + pass2, two batch-rows per block.
// Round-4 layout: 16-LANE GROUPS. Wave wv owns cores [wv*16,wv*16+16), chunked
// 4 cores at a time; lane group g=ln>>4 owns one core, lane l16=ln&15 owns
// d-slice [l16*32, l16*32+32). Dots reduce over 16 lanes (4 shfl levels, not
// 6), e lands in all lanes of the group (no broadcast), and the V-accumulate
// reuses the register-staged h values — single global pass, no A2 re-read,
// ~110 VGPRs (no spill). Chunk loops kept at unroll-1 to pin register use.
// ============================================================================
__global__ __launch_bounds__(256, 4) void fused_kernel(const float* __restrict__ HtC,
                                                       const int* __restrict__ caps,
                                                       const int* __restrict__ dists,
                                                       const float* __restrict__ Qkp,
                                                       const float* __restrict__ Mm,
                                                       const float* __restrict__ cap_emb,
                                                       const float* __restrict__ dist_emb,
                                                       const int* __restrict__ need,
                                                       float* __restrict__ out) {
  const int t = threadIdx.x;
  const int wv = t >> 6, ln = t & 63;
  const int g = ln >> 4, l16 = ln & 15;
  const int b0 = blockIdx.x << 1;

  __shared__ float qk[2][576];      // PD-padded [2][512]
  __shared__ float gks[2][576];     // PD-padded [2][512]
  __shared__ float accs[4][576];    // PD-padded per-wave Gw partials
  __shared__ float Gws[2][DH];
  __shared__ float gkp[2][2][DH];
  __shared__ float ec[CC];          // exp values (A) / reused as ulog (C)
  __shared__ float capQ[2][11], distQ[2][3];
  __shared__ float capE[11], distE[3];
  __shared__ float capG[2][11], distG[2][3];
  __shared__ float lsum_s;
  __shared__ int capsS[2][CC], distsS[2][CC];

  // ---- preload caps/dists for both rows ----
  if (t < 128) {
    int hh = t >> 6, c = t & 63;
    capsS[hh][c] = caps[(size_t)(b0 + hh) * CC + c];
    distsS[hh][c] = dists[(size_t)(b0 + hh) * CC + c];
  }

  // ---- qk for both rows: sum of 4 split-K partials (PD layout) ----
#pragma unroll
  for (int h = 0; h < 2; ++h) {
    const size_t bo = (size_t)(b0 + h) * DH;
    float q0 = 0.f, q1 = 0.f;
#pragma unroll
    for (int z = 0; z < 4; ++z) {
      q0 += Qkp[(size_t)z * NB * DH + bo + t];
      q1 += Qkp[(size_t)z * NB * DH + bo + 256 + t];
    }
    qk[h][PD(t)] = q0;
    qk[h][PD(t + 256)] = q1;
  }
  __syncthreads();

  // ---- capQ/distQ (embedding . qk) for both rows ----
#pragma unroll
  for (int h = 0; h < 2; ++h) {
#pragma unroll
    for (int r = 0; r < 3; ++r) {
      int v = wv + (r << 2);
      if (v < 11) {
        float s = 0.f;
#pragma unroll
        for (int j = 0; j < 8; ++j)
          s = fmaf(cap_emb[v * DH + ln + (j << 6)], qk[h][PD(ln + (j << 6))], s);
        s = wsum(s);
        if (ln == 0) capQ[h][v] = s;
      }
    }
    if (wv < 3) {
      float s = 0.f;
#pragma unroll
      for (int j = 0; j < 8; ++j)
        s = fmaf(dist_emb[wv * DH + ln + (j << 6)], qk[h][PD(ln + (j << 6))], s);
      s = wsum(s);
      if (ln == 0) distQ[h][wv] = s;
    }
  }

  // ---- phase A: glimpse attention over each row (single global pass) ----
  for (int h = 0; h < 2; ++h) {
    const int b = b0 + h;
    if (t < 11) capE[t] = 0.f;
    if (t < 3) distE[t] = 0.f;
    __syncthreads();   // covers capQ/distQ + capsS + qk writes on h==0
    // lane's qk slice [l16*32 .. +31] (PD(l16*32+4j) == l16*36+4j, aligned)
    float4 qs[8];
#pragma unroll
    for (int j = 0; j < 8; ++j) qs[j] = *(const float4*)&qk[h][l16 * 36 + 4 * j];
    float4 ac[8];
#pragma unroll
    for (int j = 0; j < 8; ++j) ac[j] = make_float4(0.f, 0.f, 0.f, 0.f);
    const float* hb = HtC + (size_t)b * CC * DH;
#pragma unroll 1
    for (int k = 0; k < 4; ++k) {
      const int c = (wv << 4) + (k << 2) + g;
      const float* hp = hb + (size_t)c * DH + (l16 << 5);
      float4 hv[8];
#pragma unroll
      for (int j = 0; j < 8; ++j) hv[j] = *(const float4*)&hp[4 * j];
      float s = 0.f;
#pragma unroll
      for (int j = 0; j < 8; ++j) {
        s = fmaf(hv[j].x, qs[j].x, s); s = fmaf(hv[j].y, qs[j].y, s);
        s = fmaf(hv[j].z, qs[j].z, s); s = fmaf(hv[j].w, qs[j].w, s);
      }
      // 16-lane reduce: full dot lands in every lane of the group
      s += __shfl_xor(s, 1, 64);
      s += __shfl_xor(s, 2, 64);
      s += __shfl_xor(s, 4, 64);
      s += __shfl_xor(s, 8, 64);
      float e = __expf(SCALE * (s + capQ[h][capsS[h][c]] + distQ[h][distsS[h][c]]));
      if (l16 == 0) ec[c] = e;
#pragma unroll
      for (int j = 0; j < 8; ++j) {
        ac[j].x = fmaf(e, hv[j].x, ac[j].x); ac[j].y = fmaf(e, hv[j].y, ac[j].y);
        ac[j].z = fmaf(e, hv[j].z, ac[j].z); ac[j].w = fmaf(e, hv[j].w, ac[j].w);
      }
    }
    // fold the 4 lane-groups (same d-slice lives in lanes l16, l16+16, +32, +48)
#pragma unroll
    for (int j = 0; j < 8; ++j) {
      ac[j].x += __shfl_xor(ac[j].x, 16, 64); ac[j].x += __shfl_xor(ac[j].x, 32, 64);
      ac[j].y += __shfl_xor(ac[j].y, 16, 64); ac[j].y += __shfl_xor(ac[j].y, 32, 64);
      ac[j].z += __shfl_xor(ac[j].z, 16, 64); ac[j].z += __shfl_xor(ac[j].z, 32, 64);
      ac[j].w += __shfl_xor(ac[j].w, 16, 64); ac[j].w += __shfl_xor(ac[j].w, 32, 64);
    }
    if (g == 0) {
#pragma unroll
      for (int j = 0; j < 8; ++j)
        *(float4*)&accs[wv][l16 * 36 + 4 * j] = ac[j];
    }
    __syncthreads();
    if (t < CC) {
      float e = ec[t];
      float l = wsum(e);
      if (t == 0) lsum_s = l;
      atomicAdd(&capE[capsS[h][t]], e);
      atomicAdd(&distE[distsS[h][t]], e);
    }
    __syncthreads();
    const float rinv = 1.0f / lsum_s;
#pragma unroll
    for (int dd = 0; dd < 2; ++dd) {
      int d = t + (dd << 8);
      float gg = accs[0][PD(d)] + accs[1][PD(d)] + accs[2][PD(d)] + accs[3][PD(d)];
#pragma unroll
      for (int v = 0; v < 11; ++v) gg = fmaf(capE[v], cap_emb[v * DH + d], gg);
#pragma unroll
      for (int v = 0; v < 3; ++v) gg = fmaf(distE[v], dist_emb[v * DH + d], gg);
      Gws[h][d] = gg * rinv;
    }
    __syncthreads();
  }

  // ---- phase B: gk[h] = Gw[h] @ M, M streamed once (coalesced float4) ----
  {
    const int e4 = (t & 127) << 2;   // 128 threads cover e in [0,512) as float4
    const int half = t >> 7;         // d-range split: [0,256) / [256,512)
    const float* Mp = Mm + (size_t)(half << 8) * DH + e4;
    const float* g0p = &Gws[0][half << 8];
    const float* g1p = &Gws[1][half << 8];
    float s00 = 0.f, s01 = 0.f, s02 = 0.f, s03 = 0.f;
    float s10 = 0.f, s11 = 0.f, s12 = 0.f, s13 = 0.f;
#pragma unroll 8
    for (int d = 0; d < 256; ++d) {
      float4 m4 = *(const float4*)&Mp[(size_t)d * DH];
      float g0 = g0p[d];
      float g1 = g1p[d];
      s00 = fmaf(g0, m4.x, s00); s01 = fmaf(g0, m4.y, s01);
      s02 = fmaf(g0, m4.z, s02); s03 = fmaf(g0, m4.w, s03);
      s10 = fmaf(g1, m4.x, s10); s11 = fmaf(g1, m4.y, s11);
      s12 = fmaf(g1, m4.z, s12); s13 = fmaf(g1, m4.w, s13);
    }
    gkp[half][0][e4 + 0] = s00; gkp[half][0][e4 + 1] = s01;
    gkp[half][0][e4 + 2] = s02; gkp[half][0][e4 + 3] = s03;
    gkp[half][1][e4 + 0] = s10; gkp[half][1][e4 + 1] = s11;
    gkp[half][1][e4 + 2] = s12; gkp[half][1][e4 + 3] = s13;
  }
  __syncthreads();
#pragma unroll
  for (int h = 0; h < 2; ++h) {
    gks[h][PD(t)] = gkp[0][h][t] + gkp[1][h][t];
    gks[h][PD(t + 256)] = gkp[0][h][t + 256] + gkp[1][h][t + 256];
  }
  __syncthreads();

  // ---- capG/distG (embedding . gk) for both rows ----
#pragma unroll
  for (int h = 0; h < 2; ++h) {
#pragma unroll
    for (int r = 0; r < 3; ++r) {
      int v = wv + (r << 2);
      if (v < 11) {
        float s = 0.f;
#pragma unroll
        for (int j = 0; j < 8; ++j)
          s = fmaf(cap_emb[v * DH + ln + (j << 6)], gks[h][PD(ln + (j << 6))], s);
        s = wsum(s);
        if (ln == 0) capG[h][v] = s;
      }
    }
    if (wv < 3) {
      float s = 0.f;
#pragma unroll
      for (int j = 0; j < 8; ++j)
        s = fmaf(dist_emb[wv * DH + ln + (j << 6)], gks[h][PD(ln + (j << 6))], s);
      s = wsum(s);
      if (ln == 0) distG[h][wv] = s;
    }
  }
  __syncthreads();

  // ---- phase C: pointer logits + capacity-masked softmax (b1 first) ----
  for (int h = 1; h >= 0; --h) {
    const int b = b0 + h;
    float4 gs[8];
#pragma unroll
    for (int j = 0; j < 8; ++j) gs[j] = *(const float4*)&gks[h][l16 * 36 + 4 * j];
    const float* hb = HtC + (size_t)b * CC * DH;
#pragma unroll 1
    for (int k = 0; k < 4; ++k) {
      const int c = (wv << 4) + (k << 2) + g;
      const float* hp = hb + (size_t)c * DH + (l16 << 5);
      float4 hv[8];
#pragma unroll
      for (int j = 0; j < 8; ++j) hv[j] = *(const float4*)&hp[4 * j];
      float s = 0.f;
#pragma unroll
      for (int j = 0; j < 8; ++j) {
        s = fmaf(hv[j].x, gs[j].x, s); s = fmaf(hv[j].y, gs[j].y, s);
        s = fmaf(hv[j].z, gs[j].z, s); s = fmaf(hv[j].w, gs[j].w, s);
      }
      s += __shfl_xor(s, 1, 64);
      s += __shfl_xor(s, 2, 64);
      s += __shfl_xor(s, 4, 64);
      s += __shfl_xor(s, 8, 64);
      if (l16 == 0)
        ec[c] = SCALE * (s + capG[h][capsS[h][c]] + distG[h][distsS[h][c]]);
    }
    __syncthreads();
    if (t < CC) {
      int nb = need[b];
      float x = ec[t];
      if (capsS[h][t] < nb) x = -INFINITY;
      float m = x;
#pragma unroll
      for (int off = 32; off; off >>= 1) m = fmaxf(m, __shfl_xor(m, off, 64));
      float e = __expf(x - m);
      float ssum = wsum(e);
      out[(size_t)b * CC + t] = e / ssum;
    }
    __syncthreads();
  }
}

// ---------------- launch ----------------
extern "C" void kernel_launch(void* const* d_in, const int* in_sizes, int n_in,
                              void* d_out, int out_size, void* d_ws, size_t ws_size,
                              hipStream_t stream) {
  const float* HtC      = (const float*)d_in[0];
  const int* caps       = (const int*)d_in[1];
  const int* dists      = (const int*)d_in[2];
  const float* H_X      = (const float*)d_in[3];
  const float* Ht_S     = (const float*)d_in[4];
  const float* Eq_Q     = (const float*)d_in[5];
  const unsigned char* dbl = (const unsigned char*)d_in[6];
  const float* cap_emb  = (const float*)d_in[7];
  const float* dist_emb = (const float*)d_in[8];
  const float* W_q      = (const float*)d_in[9];
  const float* W_k      = (const float*)d_in[10];
  const float* W_v      = (const float*)d_in[11];
  float* out = (float*)d_out;

  float* ws     = (float*)d_ws;
  float* wsA    = ws;                        // [1536,512]     A = W_q^T @ W_k
  float* wsM    = wsA + 1536 * 512;          // [512,512]      M = W_v^T @ W_k
  float* wsQkp  = wsM + 512 * 512;           // [4][2048,512]  Qk split-K partials
  int* wsNeed   = (int*)(wsQkp + 4 * 2048 * 512);

  pre_kernel<<<257, 128, 0, stream>>>(W_q, W_v, W_k, wsA, wsM, dbl, wsNeed);
  gemm_nn2p<<<dim3(16, 8, 4), 256, 0, stream>>>(H_X, Ht_S, Eq_Q, wsA, wsQkp, 384);
  fused_kernel<<<NB / 2, 256, 0, stream>>>(HtC, caps, dists, wsQkp, wsM,
                                           cap_emb, dist_emb, wsNeed, out);
}

// Round 5
// 534.109 us; speedup vs baseline: 1.0835x; 1.0370x over previous
//
#include <hip/hip_runtime.h>
#include <math.h>

#define DH 512
#define CC 64
#define NB 2048
#define SCALE 0.044194173824159216f   // 1/sqrt(512)

// padded index for column-sliced LDS arrays: stride 36 floats per 32-elem row
// (144 B: 16B-aligned for b128, and (36l+4j)%32 spreads banks ≤2-way = free)
#define PD(d) ((((d) >> 5) * 36) + ((d) & 31))

// ---------------- wave helpers ----------------
__device__ __forceinline__ float wsum(float v) {
#pragma unroll
  for (int off = 32; off; off >>= 1) v += __shfl_xor(v, off, 64);
  return v;
}

// ============================================================================
// pre_kernel: blocks 0..255 compute wsA = W_q^T @ W_k (rows 0..1535) and
// wsM = W_v^T @ W_k (rows 1536..2047) with 64x64 tiles; block 256 does the
// bool-layout detection for `double` -> need[b] in {1,2}.
// ============================================================================
__global__ __launch_bounds__(128) void pre_kernel(const float* __restrict__ Wq,
                                                  const float* __restrict__ Wv,
                                                  const float* __restrict__ Wk,
                                                  float* __restrict__ Aout,
                                                  float* __restrict__ Mout,
                                                  const unsigned char* __restrict__ dbl,
                                                  int* __restrict__ need) {
  const int bx = blockIdx.x;
  const int t = threadIdx.x;
  if (bx == 256) {
    __shared__ int flagNZ, flagFP;
    if (t == 0) { flagNZ = 0; flagFP = 0; }
    __syncthreads();
    int nz = 0, fp = 0;
    for (int i = t; i < NB; i += 128) {
      if (i & 3) {
        unsigned char v = dbl[i];
        nz |= (v != 0);
        fp |= (v == 0x3f) | (v == 0x80);
      }
    }
    if (nz) atomicOr(&flagNZ, 1);
    if (fp) atomicOr(&flagFP, 1);
    __syncthreads();
    const int isFP = flagFP, isByte = flagNZ && !flagFP;
    for (int i = t; i < NB; i += 128) {
      int v;
      if (isFP)        v = (((const float*)dbl)[i] != 0.0f);
      else if (isByte) v = (dbl[i] != 0);
      else             v = (((const int*)dbl)[i] != 0);
      need[i] = v ? 2 : 1;
    }
    return;
  }
  __shared__ float As[16][64];
  __shared__ float Bs[16][64];
  const int mt = bx >> 3, nt = bx & 7;
  const int m0 = mt * 64, n0 = nt * 64;
  const bool isQ = (m0 < 1536);
  const float* Acol = isQ ? (Wq + m0) : (Wv + (m0 - 1536));
  const int lda = isQ ? 1536 : 512;
  float* Cout = isQ ? (Aout + (size_t)m0 * 512) : (Mout + (size_t)(m0 - 1536) * 512);
  const int lr = t >> 3;
  const int lc = (t & 7) << 3;
  const int tx = t & 15, ty = t >> 4;

  float4 ra0, ra1, rb0, rb1;
  ra0 = *(const float4*)&Acol[(size_t)lr * lda + lc];
  ra1 = *(const float4*)&Acol[(size_t)lr * lda + lc + 4];
  rb0 = *(const float4*)&Wk[(size_t)lr * 512 + n0 + lc];
  rb1 = *(const float4*)&Wk[(size_t)lr * 512 + n0 + lc + 4];
  float acc[8][4] = {};
  for (int k0 = 0; k0 < 512; k0 += 16) {
    __syncthreads();
    *(float4*)&As[lr][lc] = ra0;
    *(float4*)&As[lr][lc + 4] = ra1;
    *(float4*)&Bs[lr][lc] = rb0;
    *(float4*)&Bs[lr][lc + 4] = rb1;
    __syncthreads();
    if (k0 + 16 < 512) {
      const int kn = k0 + 16 + lr;
      ra0 = *(const float4*)&Acol[(size_t)kn * lda + lc];
      ra1 = *(const float4*)&Acol[(size_t)kn * lda + lc + 4];
      rb0 = *(const float4*)&Wk[(size_t)kn * 512 + n0 + lc];
      rb1 = *(const float4*)&Wk[(size_t)kn * 512 + n0 + lc + 4];
    }
#pragma unroll
    for (int k = 0; k < 16; ++k) {
      float4 a0 = *(float4*)&As[k][ty << 3];
      float4 a1 = *(float4*)&As[k][(ty << 3) + 4];
      float4 b  = *(float4*)&Bs[k][tx << 2];
      float av[8] = {a0.x, a0.y, a0.z, a0.w, a1.x, a1.y, a1.z, a1.w};
      float bv[4] = {b.x, b.y, b.z, b.w};
#pragma unroll
      for (int i = 0; i < 8; ++i)
#pragma unroll
        for (int j = 0; j < 4; ++j) acc[i][j] = fmaf(av[i], bv[j], acc[i][j]);
    }
  }
#pragma unroll
  for (int i = 0; i < 8; ++i) {
    float4 o = {acc[i][0], acc[i][1], acc[i][2], acc[i][3]};
    *(float4*)&Cout[(size_t)((ty << 3) + i) * 512 + n0 + (tx << 2)] = o;
  }
}

// ============================================================================
// gemm_nn2p: 128x64 tile, 8x4 micro, reg-prefetch, split-K to PARTIAL buffers
// (only used for qk = context @ A now)
// ============================================================================
#define AS_STR 132

__global__ __launch_bounds__(256) void gemm_nn2p(const float* __restrict__ A0,
                                                 const float* __restrict__ A1,
                                                 const float* __restrict__ A2,
                                                 const float* __restrict__ B,
                                                 float* __restrict__ Cp,
                                                 int kchunk) {
  __shared__ float As[16 * AS_STR];
  __shared__ float Bs[16 * 64];
  const int t = threadIdx.x;
  const int m0 = blockIdx.x * 128, n0 = blockIdx.y * 64;
  const int kbeg = blockIdx.z * kchunk, kend = kbeg + kchunk;
  float* C = Cp + (size_t)blockIdx.z * (NB * DH);
  const int tx = t & 15, ty = t >> 4;
  const int ar0 = t >> 2;
  const int ak4 = (t & 3) << 2;
  const int bk = t >> 4, bn4 = (t & 15) << 2;

  float4 ra0, ra1, rb;
  {
    const float* base = (kbeg < 512) ? A0 : ((kbeg < 1024) ? A1 : A2);
    const int kk = kbeg & 511;
    ra0 = *(const float4*)&base[(size_t)(m0 + ar0) * 512 + kk + ak4];
    ra1 = *(const float4*)&base[(size_t)(m0 + ar0 + 64) * 512 + kk + ak4];
    rb  = *(const float4*)&B[(size_t)(kbeg + bk) * 512 + n0 + bn4];
  }
  float acc[8][4] = {};
  for (int k0 = kbeg; k0 < kend; k0 += 16) {
    __syncthreads();
    As[(ak4 + 0) * AS_STR + ar0] = ra0.x;
    As[(ak4 + 1) * AS_STR + ar0] = ra0.y;
    As[(ak4 + 2) * AS_STR + ar0] = ra0.z;
    As[(ak4 + 3) * AS_STR + ar0] = ra0.w;
    As[(ak4 + 0) * AS_STR + ar0 + 64] = ra1.x;
    As[(ak4 + 1) * AS_STR + ar0 + 64] = ra1.y;
    As[(ak4 + 2) * AS_STR + ar0 + 64] = ra1.z;
    As[(ak4 + 3) * AS_STR + ar0 + 64] = ra1.w;
    *(float4*)&Bs[bk * 64 + bn4] = rb;
    __syncthreads();
    if (k0 + 16 < kend) {
      const int kn = k0 + 16;
      const float* base = (kn < 512) ? A0 : ((kn < 1024) ? A1 : A2);
      const int kk = kn & 511;
      ra0 = *(const float4*)&base[(size_t)(m0 + ar0) * 512 + kk + ak4];
      ra1 = *(const float4*)&base[(size_t)(m0 + ar0 + 64) * 512 + kk + ak4];
      rb  = *(const float4*)&B[(size_t)(kn + bk) * 512 + n0 + bn4];
    }
#pragma unroll
    for (int k = 0; k < 16; ++k) {
      float4 a0 = *(float4*)&As[k * AS_STR + (ty << 3)];
      float4 a1 = *(float4*)&As[k * AS_STR + (ty << 3) + 4];
      float4 b  = *(float4*)&Bs[k * 64 + (tx << 2)];
      float av[8] = {a0.x, a0.y, a0.z, a0.w, a1.x, a1.y, a1.z, a1.w};
      float bv[4] = {b.x, b.y, b.z, b.w};
#pragma unroll
      for (int i = 0; i < 8; ++i)
#pragma unroll
        for (int j = 0; j < 4; ++j) acc[i][j] = fmaf(av[i], bv[j], acc[i][j]);
    }
  }
#pragma unroll
  for (int i = 0; i < 8; ++i) {
    float4 o = {acc[i][0], acc[i][1], acc[i][2], acc[i][3]};
    *(float4*)&C[(size_t)(m0 + (ty << 3) + i) * 512 + n0 + (tx << 2)] = o;
  }
}

// ============================================================================
// fused_kernel: pass1 + gemm2 + pass2, FOUR batch-rows per block (grid 512).
//  - 16-lane groups: group g owns a core, lane l16 owns d-slice [32*l16,+32).
//  - phases A and C use a manual next-chunk prefetch (hv/hvn) so global loads
//    issue ahead of the shfl/exp chain.
//  - 4 rows amortize phase B's M-read 4x: L2 traffic 2 GB -> 512 MB.
//  - __launch_bounds__(256) + waves_per_eu(2): VGPR budget 256, stops the
//    allocator's pin-to-64-and-spill behavior (R3/R4: 51-76 MB scratch).
// ============================================================================
__global__ __launch_bounds__(256)
__attribute__((amdgpu_waves_per_eu(2)))
void fused_kernel(const float* __restrict__ HtC,
                  const int* __restrict__ caps,
                  const int* __restrict__ dists,
                  const float* __restrict__ Qkp,
                  const float* __restrict__ Mm,
                  const float* __restrict__ cap_emb,
                  const float* __restrict__ dist_emb,
                  const int* __restrict__ need,
                  float* __restrict__ out) {
  const int t = threadIdx.x;
  const int wv = t >> 6, ln = t & 63;
  const int g = ln >> 4, l16 = ln & 15;
  const int b0 = blockIdx.x << 2;

  __shared__ __align__(16) float qk[4][576];    // PD-padded [4][512]
  __shared__ __align__(16) float gks[4][576];   // PD-padded [4][512]
  __shared__ __align__(16) float accs[4][576];  // PD-padded per-wave Gw partials
  __shared__ __align__(16) float Gws[4][DH];
  __shared__ __align__(16) float gkp[2][4][DH];
  __shared__ float ec[CC];          // exp values (A) / ulog (C)
  __shared__ float capQ[4][11], distQ[4][3];
  __shared__ float capE[11], distE[3];
  __shared__ float capG[4][11], distG[4][3];
  __shared__ float lsum_s;
  __shared__ int capsS[4][CC], distsS[4][CC];

  // ---- preload caps/dists for all four rows ----
  {
    const int hh = t >> 6, c = t & 63;
    capsS[hh][c] = caps[(size_t)(b0 + hh) * CC + c];
    distsS[hh][c] = dists[(size_t)(b0 + hh) * CC + c];
  }

  // ---- qk for all rows: sum of 4 split-K partials (vectorized, PD layout) ----
  {
    const int hh = t >> 6;
    const int d0 = (t & 63) << 3;    // 8 floats per thread
    const size_t bo = (size_t)(b0 + hh) * DH + d0;
    float4 q0 = make_float4(0.f, 0.f, 0.f, 0.f);
    float4 q1 = make_float4(0.f, 0.f, 0.f, 0.f);
#pragma unroll
    for (int z = 0; z < 4; ++z) {
      float4 a = *(const float4*)&Qkp[(size_t)z * NB * DH + bo];
      float4 b4 = *(const float4*)&Qkp[(size_t)z * NB * DH + bo + 4];
      q0.x += a.x; q0.y += a.y; q0.z += a.z; q0.w += a.w;
      q1.x += b4.x; q1.y += b4.y; q1.z += b4.z; q1.w += b4.w;
    }
    *(float4*)&qk[hh][PD(d0)] = q0;
    *(float4*)&qk[hh][PD(d0 + 4)] = q1;
  }
  __syncthreads();

  // ---- capQ/distQ (embedding . qk) for all rows ----
#pragma unroll
  for (int h = 0; h < 4; ++h) {
#pragma unroll
    for (int r = 0; r < 3; ++r) {
      int v = wv + (r << 2);
      if (v < 11) {
        float s = 0.f;
#pragma unroll
        for (int j = 0; j < 8; ++j)
          s = fmaf(cap_emb[v * DH + ln + (j << 6)], qk[h][PD(ln + (j << 6))], s);
        s = wsum(s);
        if (ln == 0) capQ[h][v] = s;
      }
    }
    if (wv < 3) {
      float s = 0.f;
#pragma unroll
      for (int j = 0; j < 8; ++j)
        s = fmaf(dist_emb[wv * DH + ln + (j << 6)], qk[h][PD(ln + (j << 6))], s);
      s = wsum(s);
      if (ln == 0) distQ[h][wv] = s;
    }
  }

  const int coff = l16 << 5;

  // ---- phase A: glimpse attention per row (prefetched single global pass) ----
  for (int h = 0; h < 4; ++h) {
    const int b = b0 + h;
    if (t < 11) capE[t] = 0.f;
    if (t < 3) distE[t] = 0.f;
    __syncthreads();   // covers reset + (h==0: capQ/distQ/capsS/qk writes)
    float4 qs[8];
#pragma unroll
    for (int j = 0; j < 8; ++j) qs[j] = *(const float4*)&qk[h][l16 * 36 + 4 * j];
    float4 ac[8];
#pragma unroll
    for (int j = 0; j < 8; ++j) ac[j] = make_float4(0.f, 0.f, 0.f, 0.f);
    const float* hb = HtC + (size_t)b * CC * DH;
    float4 hv[8];
    {
      const float* hp = hb + (size_t)((wv << 4) + g) * DH + coff;
#pragma unroll
      for (int j = 0; j < 8; ++j) hv[j] = *(const float4*)&hp[4 * j];
    }
#pragma unroll 1
    for (int k = 0; k < 4; ++k) {
      const int c = (wv << 4) + (k << 2) + g;
      float4 hvn[8];
      if (k < 3) {
        const float* hp = hb + (size_t)(c + 4) * DH + coff;
#pragma unroll
        for (int j = 0; j < 8; ++j) hvn[j] = *(const float4*)&hp[4 * j];
      }
      float s = 0.f;
#pragma unroll
      for (int j = 0; j < 8; ++j) {
        s = fmaf(hv[j].x, qs[j].x, s); s = fmaf(hv[j].y, qs[j].y, s);
        s = fmaf(hv[j].z, qs[j].z, s); s = fmaf(hv[j].w, qs[j].w, s);
      }
      s += __shfl_xor(s, 1, 64);
      s += __shfl_xor(s, 2, 64);
      s += __shfl_xor(s, 4, 64);
      s += __shfl_xor(s, 8, 64);
      float e = __expf(SCALE * (s + capQ[h][capsS[h][c]] + distQ[h][distsS[h][c]]));
      if (l16 == 0) ec[c] = e;
#pragma unroll
      for (int j = 0; j < 8; ++j) {
        ac[j].x = fmaf(e, hv[j].x, ac[j].x); ac[j].y = fmaf(e, hv[j].y, ac[j].y);
        ac[j].z = fmaf(e, hv[j].z, ac[j].z); ac[j].w = fmaf(e, hv[j].w, ac[j].w);
      }
      if (k < 3) {
#pragma unroll
        for (int j = 0; j < 8; ++j) hv[j] = hvn[j];
      }
    }
    // fold the 4 lane-groups (same d-slice lives in lanes l16, +16, +32, +48)
#pragma unroll
    for (int j = 0; j < 8; ++j) {
      ac[j].x += __shfl_xor(ac[j].x, 16, 64); ac[j].x += __shfl_xor(ac[j].x, 32, 64);
      ac[j].y += __shfl_xor(ac[j].y, 16, 64); ac[j].y += __shfl_xor(ac[j].y, 32, 64);
      ac[j].z += __shfl_xor(ac[j].z, 16, 64); ac[j].z += __shfl_xor(ac[j].z, 32, 64);
      ac[j].w += __shfl_xor(ac[j].w, 16, 64); ac[j].w += __shfl_xor(ac[j].w, 32, 64);
    }
    if (g == 0) {
#pragma unroll
      for (int j = 0; j < 8; ++j)
        *(float4*)&accs[wv][l16 * 36 + 4 * j] = ac[j];
    }
    __syncthreads();
    if (t < CC) {
      float e = ec[t];
      float l = wsum(e);
      if (t == 0) lsum_s = l;
      atomicAdd(&capE[capsS[h][t]], e);
      atomicAdd(&distE[distsS[h][t]], e);
    }
    __syncthreads();
    const float rinv = 1.0f / lsum_s;
#pragma unroll
    for (int dd = 0; dd < 2; ++dd) {
      int d = t + (dd << 8);
      float gg = accs[0][PD(d)] + accs[1][PD(d)] + accs[2][PD(d)] + accs[3][PD(d)];
#pragma unroll
      for (int v = 0; v < 11; ++v) gg = fmaf(capE[v], cap_emb[v * DH + d], gg);
#pragma unroll
      for (int v = 0; v < 3; ++v) gg = fmaf(distE[v], dist_emb[v * DH + d], gg);
      Gws[h][d] = gg * rinv;
    }
    __syncthreads();
  }

  // ---- phase B: gk[h] = Gw[h] @ M, M read once per block for 4 rows ----
  {
    const int e4 = (t & 127) << 2;   // 128 threads cover e in [0,512) as float4
    const int half = t >> 7;         // d-range split: [0,256) / [256,512)
    const float* Mp = Mm + (size_t)(half << 8) * DH + e4;
    const float* gw0 = &Gws[0][half << 8];
    const float* gw1 = &Gws[1][half << 8];
    const float* gw2 = &Gws[2][half << 8];
    const float* gw3 = &Gws[3][half << 8];
    float4 s0 = make_float4(0.f, 0.f, 0.f, 0.f);
    float4 s1 = s0, s2 = s0, s3 = s0;
#pragma unroll 4
    for (int d = 0; d < 256; ++d) {
      float4 m4 = *(const float4*)&Mp[(size_t)d * DH];
      float g0 = gw0[d], g1 = gw1[d], g2 = gw2[d], g3 = gw3[d];
      s0.x = fmaf(g0, m4.x, s0.x); s0.y = fmaf(g0, m4.y, s0.y);
      s0.z = fmaf(g0, m4.z, s0.z); s0.w = fmaf(g0, m4.w, s0.w);
      s1.x = fmaf(g1, m4.x, s1.x); s1.y = fmaf(g1, m4.y, s1.y);
      s1.z = fmaf(g1, m4.z, s1.z); s1.w = fmaf(g1, m4.w, s1.w);
      s2.x = fmaf(g2, m4.x, s2.x); s2.y = fmaf(g2, m4.y, s2.y);
      s2.z = fmaf(g2, m4.z, s2.z); s2.w = fmaf(g2, m4.w, s2.w);
      s3.x = fmaf(g3, m4.x, s3.x); s3.y = fmaf(g3, m4.y, s3.y);
      s3.z = fmaf(g3, m4.z, s3.z); s3.w = fmaf(g3, m4.w, s3.w);
    }
    *(float4*)&gkp[half][0][e4] = s0;
    *(float4*)&gkp[half][1][e4] = s1;
    *(float4*)&gkp[half][2][e4] = s2;
    *(float4*)&gkp[half][3][e4] = s3;
  }
  __syncthreads();
#pragma unroll
  for (int h = 0; h < 4; ++h) {
    gks[h][PD(t)] = gkp[0][h][t] + gkp[1][h][t];
    gks[h][PD(t + 256)] = gkp[0][h][t + 256] + gkp[1][h][t + 256];
  }
  __syncthreads();

  // ---- capG/distG (embedding . gk) for all rows ----
#pragma unroll
  for (int h = 0; h < 4; ++h) {
#pragma unroll
    for (int r = 0; r < 3; ++r) {
      int v = wv + (r << 2);
      if (v < 11) {
        float s = 0.f;
#pragma unroll
        for (int j = 0; j < 8; ++j)
          s = fmaf(cap_emb[v * DH + ln + (j << 6)], gks[h][PD(ln + (j << 6))], s);
        s = wsum(s);
        if (ln == 0) capG[h][v] = s;
      }
    }
    if (wv < 3) {
      float s = 0.f;
#pragma unroll
      for (int j = 0; j < 8; ++j)
        s = fmaf(dist_emb[wv * DH + ln + (j << 6)], gks[h][PD(ln + (j << 6))], s);
      s = wsum(s);
      if (ln == 0) distG[h][wv] = s;
    }
  }
  __syncthreads();

  // ---- phase C: pointer logits + masked softmax (freshest row first) ----
  for (int h = 3; h >= 0; --h) {
    const int b = b0 + h;
    float4 gs[8];
#pragma unroll
    for (int j = 0; j < 8; ++j) gs[j] = *(const float4*)&gks[h][l16 * 36 + 4 * j];
    const float* hb = HtC + (size_t)b * CC * DH;
    float4 hv[8];
    {
      const float* hp = hb + (size_t)((wv << 4) + g) * DH + coff;
#pragma unroll
      for (int j = 0; j < 8; ++j) hv[j] = *(const float4*)&hp[4 * j];
    }
#pragma unroll 1
    for (int k = 0; k < 4; ++k) {
      const int c = (wv << 4) + (k << 2) + g;
      float4 hvn[8];
      if (k < 3) {
        const float* hp = hb + (size_t)(c + 4) * DH + coff;
#pragma unroll
        for (int j = 0; j < 8; ++j) hvn[j] = *(const float4*)&hp[4 * j];
      }
      float s = 0.f;
#pragma unroll
      for (int j = 0; j < 8; ++j) {
        s = fmaf(hv[j].x, gs[j].x, s); s = fmaf(hv[j].y, gs[j].y, s);
        s = fmaf(hv[j].z, gs[j].z, s); s = fmaf(hv[j].w, gs[j].w, s);
      }
      s += __shfl_xor(s, 1, 64);
      s += __shfl_xor(s, 2, 64);
      s += __shfl_xor(s, 4, 64);
      s += __shfl_xor(s, 8, 64);
      if (l16 == 0)
        ec[c] = SCALE * (s + capG[h][capsS[h][c]] + distG[h][distsS[h][c]]);
      if (k < 3) {
#pragma unroll
        for (int j = 0; j < 8; ++j) hv[j] = hvn[j];
      }
    }
    __syncthreads();
    if (t < CC) {
      int nb = need[b];
      float x = ec[t];
      if (capsS[h][t] < nb) x = -INFINITY;
      float m = x;
#pragma unroll
      for (int off = 32; off; off >>= 1) m = fmaxf(m, __shfl_xor(m, off, 64));
      float e = __expf(x - m);
      float ssum = wsum(e);
      out[(size_t)b * CC + t] = e / ssum;
    }
    __syncthreads();
  }
}

// ---------------- launch ----------------
extern "C" void kernel_launch(void* const* d_in, const int* in_sizes, int n_in,
                              void* d_out, int out_size, void* d_ws, size_t ws_size,
                              hipStream_t stream) {
  const float* HtC      = (const float*)d_in[0];
  const int* caps       = (const int*)d_in[1];
  const int* dists      = (const int*)d_in[2];
  const float* H_X      = (const float*)d_in[3];
  const float* Ht_S     = (const float*)d_in[4];
  const float* Eq_Q     = (const float*)d_in[5];
  const unsigned char* dbl = (const unsigned char*)d_in[6];
  const float* cap_emb  = (const float*)d_in[7];
  const float* dist_emb = (const float*)d_in[8];
  const float* W_q      = (const float*)d_in[9];
  const float* W_k      = (const float*)d_in[10];
  const float* W_v      = (const float*)d_in[11];
  float* out = (float*)d_out;

  float* ws     = (float*)d_ws;
  float* wsA    = ws;                        // [1536,512]     A = W_q^T @ W_k
  float* wsM    = wsA + 1536 * 512;          // [512,512]      M = W_v^T @ W_k
  float* wsQkp  = wsM + 512 * 512;           // [4][2048,512]  Qk split-K partials
  int* wsNeed   = (int*)(wsQkp + 4 * 2048 * 512);

  pre_kernel<<<257, 128, 0, stream>>>(W_q, W_v, W_k, wsA, wsM, dbl, wsNeed);
  gemm_nn2p<<<dim3(16, 8, 4), 256, 0, stream>>>(H_X, Ht_S, Eq_Q, wsA, wsQkp, 384);
  fused_kernel<<<NB / 4, 256, 0, stream>>>(HtC, caps, dists, wsQkp, wsM,
                                           cap_emb, dist_emb, wsNeed, out);
}